// Round 1
// 415.826 us; speedup vs baseline: 1.0085x; 1.0085x over previous
//
#include <hip/hip_runtime.h>
#include <math.h>

// Problem constants (S, B, D from reference).
#define S_LEN    2048
#define BATCH    32
#define DIM      1024
#define P_CHUNKS 32                 // seq chunks (blocks per batch)
#define CHUNK    (S_LEN / P_CHUNKS) // 64 rows per block
#define ROWS_PER_WAVE (CHUNK / 4)   // 16 rows per wave
#define NPART    (P_CHUNKS * 4)     // 128 flash partials per batch

// ---------------------------------------------------------------------------
// Skinny GEMM: out[b][d] = act( sum_k A[b][k] * W[d][k] ), b in [0,32).
// One wave per output column d (4 waves/block -> grid = Dout/4 blocks).
// A (32 x K) is staged in LDS in 256-wide K tiles, double-buffered; the
// next tile's staging registers AND the next W fragment are prefetched
// during compute so global loads stay in flight across the barrier.
// act: 0 = identity, 1 = tanh.
// ---------------------------------------------------------------------------
__global__ __launch_bounds__(256) void gemm_skinny(
    const float* __restrict__ A, const float* __restrict__ W,
    float* __restrict__ out, int K, int Dout, int act)
{
    __shared__ __align__(16) float At[2][32 * 256];  // 2 x 32 KiB

    const int t    = threadIdx.x;
    const int lane = t & 63;
    const int wid  = t >> 6;
    const int d    = blockIdx.x * 4 + wid;

    float acc[32];
#pragma unroll
    for (int b = 0; b < 32; ++b) acc[b] = 0.0f;

    // Preload tile 0 staging regs + this wave's W fragment for tile 0.
    float4 sreg[8];
#pragma unroll
    for (int i = 0; i < 8; ++i) {
        int f4id = t + i * 256;
        int bb   = f4id >> 6;       // row (batch)
        int c4   = f4id & 63;       // float4 column within tile
        sreg[i] = ((const float4*)(A + (size_t)bb * K))[c4];
    }
    float4 w4 = ((const float4*)(W + (size_t)d * K))[lane];

    int buf = 0;
    for (int k0 = 0; k0 < K; k0 += 256) {
        // Commit staged regs into LDS[buf].
#pragma unroll
        for (int i = 0; i < 8; ++i) {
            int f4id = t + i * 256;
            int bb   = f4id >> 6;
            int c4   = f4id & 63;
            ((float4*)At[buf])[bb * 64 + c4] = sreg[i];
        }
        __syncthreads();

        float4 w4c = w4;
        // Prefetch next tile (regs + W) while we compute this one.
        if (k0 + 256 < K) {
            const int k1 = k0 + 256;
#pragma unroll
            for (int i = 0; i < 8; ++i) {
                int f4id = t + i * 256;
                int bb   = f4id >> 6;
                int c4   = f4id & 63;
                sreg[i] = ((const float4*)(A + (size_t)bb * K + k1))[c4];
            }
            w4 = ((const float4*)(W + (size_t)d * K + k1))[lane];
        }

#pragma unroll
        for (int b = 0; b < 32; ++b) {
            float4 a4 = ((const float4*)At[buf])[b * 64 + lane];
            acc[b] = fmaf(w4c.x, a4.x, acc[b]);
            acc[b] = fmaf(w4c.y, a4.y, acc[b]);
            acc[b] = fmaf(w4c.z, a4.z, acc[b]);
            acc[b] = fmaf(w4c.w, a4.w, acc[b]);
        }
        buf ^= 1;
        // No second barrier needed: next iteration writes the OTHER buffer;
        // the single barrier per tile orders write(buf)/read(buf) correctly.
    }

    // Reduce each acc[b] across the 64 lanes; lane b keeps batch b's result.
    float mine = 0.0f;
#pragma unroll
    for (int b = 0; b < 32; ++b) {
        float v = acc[b];
#pragma unroll
        for (int off = 32; off > 0; off >>= 1) v += __shfl_xor(v, off, 64);
        if (lane == b) mine = v;
    }
    if (lane < 32) {
        float o = act ? tanhf(mine) : mine;
        out[(size_t)lane * Dout + d] = o;
    }
}

// ---------------------------------------------------------------------------
// Flash-style fused logits + online softmax + weighted-sum partials.
// WAVE-INDEPENDENT: each of the 4 waves in a block owns 16 seq rows and the
// full 1024-wide feature dim (4 x float4 per lane). Dot reduce is 6 in-wave
// shuffles; NO LDS, NO __syncthreads anywhere in the hot loop. Each wave
// writes its own partial (m, l, acc[1024]) -> 128 partials per batch.
// ---------------------------------------------------------------------------
__global__ __launch_bounds__(256) void attn_partial(
    const float* __restrict__ input, const float* __restrict__ semi,
    float* __restrict__ pacc, float* __restrict__ pm, float* __restrict__ pl)
{
    const int p    = blockIdx.x;   // seq chunk
    const int b    = blockIdx.y;   // batch
    const int t    = threadIdx.x;
    const int lane = t & 63;
    const int w    = t >> 6;
    const int part = p * 4 + w;                    // partial index [0,128)
    const int s0   = p * CHUNK + w * ROWS_PER_WAVE;

    // semi[b] fragment: 4 float4 per lane covering all 1024 features.
    const float4* sp = (const float4*)(semi + (size_t)b * DIM);
    const float4 sm0 = sp[lane];
    const float4 sm1 = sp[lane + 64];
    const float4 sm2 = sp[lane + 128];
    const float4 sm3 = sp[lane + 192];

    const float4* rp = (const float4*)(input + ((size_t)s0 * BATCH + b) * DIM);
    const size_t rstride = (size_t)BATCH * DIM / 4;  // 8192 float4 / seq row

    float m = -INFINITY, l = 0.0f;
    float4 a0 = make_float4(0.f, 0.f, 0.f, 0.f);
    float4 a1 = a0, a2 = a0, a3 = a0;

    // Prefetch row 0.
    float4 x0 = rp[lane], x1 = rp[lane + 64], x2 = rp[lane + 128], x3 = rp[lane + 192];

#pragma unroll 1
    for (int j = 0; j < ROWS_PER_WAVE; ++j) {
        const float4 c0 = x0, c1 = x1, c2 = x2, c3 = x3;
        if (j + 1 < ROWS_PER_WAVE) {
            const float4* np = rp + (size_t)(j + 1) * rstride;
            x0 = np[lane];       x1 = np[lane + 64];
            x2 = np[lane + 128]; x3 = np[lane + 192];
        }

        // 16-element partial dot for this lane.
        float pd = c0.x * sm0.x;
        pd = fmaf(c0.y, sm0.y, pd); pd = fmaf(c0.z, sm0.z, pd); pd = fmaf(c0.w, sm0.w, pd);
        pd = fmaf(c1.x, sm1.x, pd); pd = fmaf(c1.y, sm1.y, pd);
        pd = fmaf(c1.z, sm1.z, pd); pd = fmaf(c1.w, sm1.w, pd);
        pd = fmaf(c2.x, sm2.x, pd); pd = fmaf(c2.y, sm2.y, pd);
        pd = fmaf(c2.z, sm2.z, pd); pd = fmaf(c2.w, sm2.w, pd);
        pd = fmaf(c3.x, sm3.x, pd); pd = fmaf(c3.y, sm3.y, pd);
        pd = fmaf(c3.z, sm3.z, pd); pd = fmaf(c3.w, sm3.w, pd);

        // Full-wave butterfly: every lane ends with the row logit.
#pragma unroll
        for (int off = 32; off > 0; off >>= 1) pd += __shfl_xor(pd, off, 64);

        // Online softmax update (exp(-inf - mn) = 0 handles the first row).
        const float mn = fmaxf(m, pd);
        const float sc = __expf(m - mn);
        const float f  = __expf(pd - mn);
        a0.x = fmaf(f, c0.x, a0.x * sc); a0.y = fmaf(f, c0.y, a0.y * sc);
        a0.z = fmaf(f, c0.z, a0.z * sc); a0.w = fmaf(f, c0.w, a0.w * sc);
        a1.x = fmaf(f, c1.x, a1.x * sc); a1.y = fmaf(f, c1.y, a1.y * sc);
        a1.z = fmaf(f, c1.z, a1.z * sc); a1.w = fmaf(f, c1.w, a1.w * sc);
        a2.x = fmaf(f, c2.x, a2.x * sc); a2.y = fmaf(f, c2.y, a2.y * sc);
        a2.z = fmaf(f, c2.z, a2.z * sc); a2.w = fmaf(f, c2.w, a2.w * sc);
        a3.x = fmaf(f, c3.x, a3.x * sc); a3.y = fmaf(f, c3.y, a3.y * sc);
        a3.z = fmaf(f, c3.z, a3.z * sc); a3.w = fmaf(f, c3.w, a3.w * sc);
        l = fmaf(l, sc, f);
        m = mn;
    }

    float4* op = (float4*)(pacc + ((size_t)b * NPART + part) * DIM);
    op[lane]       = a0;
    op[lane + 64]  = a1;
    op[lane + 128] = a2;
    op[lane + 192] = a3;
    if (lane == 0) {
        pm[b * NPART + part] = m;
        pl[b * NPART + part] = l;
    }
}

// ---------------------------------------------------------------------------
// Combine 128 partials for batch b; write s_tilde into cat[:, :1024] and copy
// h into cat[:, 1024:]. Grid (32 batches x 4 d-quarters), 256 threads.
// ---------------------------------------------------------------------------
__global__ __launch_bounds__(256) void combine(
    const float* __restrict__ pacc, const float* __restrict__ pm,
    const float* __restrict__ pl, const float* __restrict__ h,
    float* __restrict__ cat)
{
    const int b = blockIdx.x;
    const int q = blockIdx.y;
    const int t = threadIdx.x;

    __shared__ float fsc[NPART];
    __shared__ float smv[NPART], slv[NPART];
    __shared__ float Linv;

    if (t < NPART) {
        smv[t] = pm[b * NPART + t];
        slv[t] = pl[b * NPART + t];
    }
    __syncthreads();

    // Wave 0 computes global max M and denominator L in parallel.
    if (t < 64) {
        const float m0 = smv[t], m1 = smv[t + 64];
        float mx = fmaxf(m0, m1);
#pragma unroll
        for (int off = 32; off > 0; off >>= 1) mx = fmaxf(mx, __shfl_xor(mx, off, 64));
        const float f0 = __expf(m0 - mx);
        const float f1 = __expf(m1 - mx);
        fsc[t]      = f0;
        fsc[t + 64] = f1;
        float L = fmaf(slv[t], f0, slv[t + 64] * f1);
#pragma unroll
        for (int off = 32; off > 0; off >>= 1) L += __shfl_xor(L, off, 64);
        if (t == 0) Linv = 1.0f / L;
    }
    __syncthreads();

    const int d = q * 256 + t;
    const float* pb = pacc + (size_t)b * NPART * DIM + d;
    float s0 = 0.f, s1 = 0.f, s2 = 0.f, s3 = 0.f;
#pragma unroll
    for (int pp = 0; pp < NPART; pp += 4) {
        s0 = fmaf(fsc[pp + 0], pb[(size_t)(pp + 0) * DIM], s0);
        s1 = fmaf(fsc[pp + 1], pb[(size_t)(pp + 1) * DIM], s1);
        s2 = fmaf(fsc[pp + 2], pb[(size_t)(pp + 2) * DIM], s2);
        s3 = fmaf(fsc[pp + 3], pb[(size_t)(pp + 3) * DIM], s3);
    }
    const float sum = (s0 + s1) + (s2 + s3);

    cat[(size_t)b * (2 * DIM) + d]       = sum * Linv;
    cat[(size_t)b * (2 * DIM) + DIM + d] = h[(size_t)b * DIM + d];
}

// ---------------------------------------------------------------------------
extern "C" void kernel_launch(void* const* d_in, const int* in_sizes, int n_in,
                              void* d_out, int out_size, void* d_ws, size_t ws_size,
                              hipStream_t stream)
{
    const float* input = (const float*)d_in[0];  // [S, B, D]
    const float* h     = (const float*)d_in[1];  // [B, D]
    const float* Wi    = (const float*)d_in[2];  // [D, D]
    const float* Wo    = (const float*)d_in[3];  // [D, 2D]
    float* out = (float*)d_out;                  // [B, D]

    // Workspace carve (floats): semi | pacc | pm | pl | cat  (~17 MiB)
    float* ws   = (float*)d_ws;
    float* semi = ws;                                       // 32*1024
    float* pacc = semi + 32 * 1024;                         // 32*128*1024
    float* pm   = pacc + (size_t)32 * NPART * 1024;         // 32*128
    float* pl   = pm + 32 * NPART;                          // 32*128
    float* cat  = pl + 32 * NPART;                          // 32*2048

    // 1) semi = h @ Wi.T   (K=1024, Dout=1024)
    hipLaunchKernelGGL(gemm_skinny, dim3(256), dim3(256), 0, stream,
                       h, Wi, semi, 1024, 1024, 0);
    // 2) fused logits + online softmax + weighted-sum partials (reads input once)
    hipLaunchKernelGGL(attn_partial, dim3(P_CHUNKS, BATCH), dim3(256), 0, stream,
                       input, semi, pacc, pm, pl);
    // 3) combine partials -> cat = [s_tilde, h]
    hipLaunchKernelGGL(combine, dim3(BATCH, 4), dim3(256), 0, stream,
                       pacc, pm, pl, h, cat);
    // 4) out = tanh(cat @ Wo.T)   (K=2048, Dout=1024)
    hipLaunchKernelGGL(gemm_skinny, dim3(256), dim3(256), 0, stream,
                       cat, Wo, out, 2048, 1024, 1);
}

// Round 3
// 413.768 us; speedup vs baseline: 1.0136x; 1.0050x over previous
//
#include <hip/hip_runtime.h>
#include <math.h>

// Problem constants (S, B, D from reference).
#define S_LEN    2048
#define BATCH    32
#define DIM      1024
#define P_CHUNKS 32                 // seq chunks (blocks per batch)
#define CHUNK    (S_LEN / P_CHUNKS) // 64 rows per block
#define ROWS_PER_WAVE (CHUNK / 4)   // 16 rows per wave

// ---------------------------------------------------------------------------
// Skinny GEMM: out[b][d] = act( sum_k A[b][k] * W[d][k] ), b in [0,32).
// One wave per output column d (4 waves/block -> grid = Dout/4 blocks).
// A (32 x K) is staged in LDS in 256-wide K tiles, double-buffered; the
// next tile's staging registers AND the next W fragment are prefetched
// during compute so global loads stay in flight across the barrier.
// act: 0 = identity, 1 = tanh.
// ---------------------------------------------------------------------------
__global__ __launch_bounds__(256) void gemm_skinny(
    const float* __restrict__ A, const float* __restrict__ W,
    float* __restrict__ out, int K, int Dout, int act)
{
    __shared__ __align__(16) float At[2][32 * 256];  // 2 x 32 KiB

    const int t    = threadIdx.x;
    const int lane = t & 63;
    const int wid  = t >> 6;
    const int d    = blockIdx.x * 4 + wid;

    float acc[32];
#pragma unroll
    for (int b = 0; b < 32; ++b) acc[b] = 0.0f;

    // Preload tile 0 staging regs + this wave's W fragment for tile 0.
    float4 sreg[8];
#pragma unroll
    for (int i = 0; i < 8; ++i) {
        int f4id = t + i * 256;
        int bb   = f4id >> 6;       // row (batch)
        int c4   = f4id & 63;       // float4 column within tile
        sreg[i] = ((const float4*)(A + (size_t)bb * K))[c4];
    }
    float4 w4 = ((const float4*)(W + (size_t)d * K))[lane];

    int buf = 0;
    for (int k0 = 0; k0 < K; k0 += 256) {
        // Commit staged regs into LDS[buf].
#pragma unroll
        for (int i = 0; i < 8; ++i) {
            int f4id = t + i * 256;
            int bb   = f4id >> 6;
            int c4   = f4id & 63;
            ((float4*)At[buf])[bb * 64 + c4] = sreg[i];
        }
        __syncthreads();

        float4 w4c = w4;
        // Prefetch next tile (regs + W) while we compute this one.
        if (k0 + 256 < K) {
            const int k1 = k0 + 256;
#pragma unroll
            for (int i = 0; i < 8; ++i) {
                int f4id = t + i * 256;
                int bb   = f4id >> 6;
                int c4   = f4id & 63;
                sreg[i] = ((const float4*)(A + (size_t)bb * K + k1))[c4];
            }
            w4 = ((const float4*)(W + (size_t)d * K + k1))[lane];
        }

#pragma unroll
        for (int b = 0; b < 32; ++b) {
            float4 a4 = ((const float4*)At[buf])[b * 64 + lane];
            acc[b] = fmaf(w4c.x, a4.x, acc[b]);
            acc[b] = fmaf(w4c.y, a4.y, acc[b]);
            acc[b] = fmaf(w4c.z, a4.z, acc[b]);
            acc[b] = fmaf(w4c.w, a4.w, acc[b]);
        }
        buf ^= 1;
        // Single barrier per tile is safe: iteration i+1 writes the OTHER
        // buffer, and barrier_i guarantees all waves finished reading it.
    }

    // Reduce each acc[b] across the 64 lanes; lane b keeps batch b's result.
    float mine = 0.0f;
#pragma unroll
    for (int b = 0; b < 32; ++b) {
        float v = acc[b];
#pragma unroll
        for (int off = 32; off > 0; off >>= 1) v += __shfl_xor(v, off, 64);
        if (lane == b) mine = v;
    }
    if (lane < 32) {
        float o = act ? tanhf(mine) : mine;
        out[(size_t)lane * Dout + d] = o;
    }
}

// ---------------------------------------------------------------------------
// Flash-style fused logits + online softmax + weighted-sum partials.
// Each of the 4 waves owns 16 seq rows and the full 1024-wide feature dim
// (4 x float4 per lane); dot reduce is 6 in-wave shuffles, no barriers in
// the hot loop. Defer-rescale (THR=8): the post-reduce logit is wave-
// uniform, so the rescale branch is uniform and rare; P-terms are bounded
// by e^8 which f32 accumulation tolerates (renormalized at combine).
// The 4 wave-partials are merged in LDS at block end -> ONE partial
// (m, l, acc[1024]) per (b, chunk): pacc traffic drops 4x vs per-wave.
// ---------------------------------------------------------------------------
__global__ __launch_bounds__(256) void attn_partial(
    const float* __restrict__ input, const float* __restrict__ semi,
    float* __restrict__ pacc, float* __restrict__ pm, float* __restrict__ pl)
{
    const int p    = blockIdx.x;   // seq chunk
    const int b    = blockIdx.y;   // batch
    const int t    = threadIdx.x;
    const int lane = t & 63;
    const int w    = t >> 6;
    const int s0   = p * CHUNK + w * ROWS_PER_WAVE;

    __shared__ __align__(16) float accs[4][DIM];   // 16 KiB
    __shared__ float smw[4], slw[4];

    // semi[b] fragment: 4 float4 per lane covering all 1024 features.
    const float4* sp = (const float4*)(semi + (size_t)b * DIM);
    const float4 sm0 = sp[lane];
    const float4 sm1 = sp[lane + 64];
    const float4 sm2 = sp[lane + 128];
    const float4 sm3 = sp[lane + 192];

    const float4* rp = (const float4*)(input + ((size_t)s0 * BATCH + b) * DIM);
    const size_t rstride = (size_t)BATCH * DIM / 4;  // 8192 float4 / seq row

    float m = -INFINITY, l = 0.0f;
    float4 a0 = make_float4(0.f, 0.f, 0.f, 0.f);
    float4 a1 = a0, a2 = a0, a3 = a0;

    // Prefetch row 0.
    float4 x0 = rp[lane], x1 = rp[lane + 64], x2 = rp[lane + 128], x3 = rp[lane + 192];

#pragma unroll 1
    for (int j = 0; j < ROWS_PER_WAVE; ++j) {
        const float4 c0 = x0, c1 = x1, c2 = x2, c3 = x3;
        if (j + 1 < ROWS_PER_WAVE) {
            const float4* np = rp + (size_t)(j + 1) * rstride;
            x0 = np[lane];       x1 = np[lane + 64];
            x2 = np[lane + 128]; x3 = np[lane + 192];
        }

        // 16-element partial dot for this lane.
        float pd = c0.x * sm0.x;
        pd = fmaf(c0.y, sm0.y, pd); pd = fmaf(c0.z, sm0.z, pd); pd = fmaf(c0.w, sm0.w, pd);
        pd = fmaf(c1.x, sm1.x, pd); pd = fmaf(c1.y, sm1.y, pd);
        pd = fmaf(c1.z, sm1.z, pd); pd = fmaf(c1.w, sm1.w, pd);
        pd = fmaf(c2.x, sm2.x, pd); pd = fmaf(c2.y, sm2.y, pd);
        pd = fmaf(c2.z, sm2.z, pd); pd = fmaf(c2.w, sm2.w, pd);
        pd = fmaf(c3.x, sm3.x, pd); pd = fmaf(c3.y, sm3.y, pd);
        pd = fmaf(c3.w, sm3.w, pd); pd = fmaf(c3.z, sm3.z, pd);

        // Full-wave butterfly: every lane ends with the row logit (uniform).
#pragma unroll
        for (int off = 32; off > 0; off >>= 1) pd += __shfl_xor(pd, off, 64);

        // Defer-rescale online softmax (wave-uniform branch).
        if (pd > m + 8.0f) {
            const float sc = __expf(m - pd);   // exp(-inf) = 0 on first row
            a0.x *= sc; a0.y *= sc; a0.z *= sc; a0.w *= sc;
            a1.x *= sc; a1.y *= sc; a1.z *= sc; a1.w *= sc;
            a2.x *= sc; a2.y *= sc; a2.z *= sc; a2.w *= sc;
            a3.x *= sc; a3.y *= sc; a3.z *= sc; a3.w *= sc;
            l *= sc;
            m = pd;
        }
        const float f = __expf(pd - m);        // bounded by e^8
        a0.x = fmaf(f, c0.x, a0.x); a0.y = fmaf(f, c0.y, a0.y);
        a0.z = fmaf(f, c0.z, a0.z); a0.w = fmaf(f, c0.w, a0.w);
        a1.x = fmaf(f, c1.x, a1.x); a1.y = fmaf(f, c1.y, a1.y);
        a1.z = fmaf(f, c1.z, a1.z); a1.w = fmaf(f, c1.w, a1.w);
        a2.x = fmaf(f, c2.x, a2.x); a2.y = fmaf(f, c2.y, a2.y);
        a2.z = fmaf(f, c2.z, a2.z); a2.w = fmaf(f, c2.w, a2.w);
        a3.x = fmaf(f, c3.x, a3.x); a3.y = fmaf(f, c3.y, a3.y);
        a3.z = fmaf(f, c3.z, a3.z); a3.w = fmaf(f, c3.w, a3.w);
        l += f;
    }

    // ---- block-level combine: 4 wave-partials -> 1 chunk-partial ----
    float4* as = (float4*)accs[w];
    as[lane]       = a0;
    as[lane + 64]  = a1;
    as[lane + 128] = a2;
    as[lane + 192] = a3;
    if (lane == 0) { smw[w] = m; slw[w] = l; }
    __syncthreads();

    const float M  = fmaxf(fmaxf(smw[0], smw[1]), fmaxf(smw[2], smw[3]));
    const float f0 = __expf(smw[0] - M);
    const float f1 = __expf(smw[1] - M);
    const float f2 = __expf(smw[2] - M);
    const float f3 = __expf(smw[3] - M);

    const float4 r0 = ((const float4*)accs[0])[t];
    const float4 r1 = ((const float4*)accs[1])[t];
    const float4 r2 = ((const float4*)accs[2])[t];
    const float4 r3 = ((const float4*)accs[3])[t];
    float4 o;
    o.x = fmaf(f3, r3.x, fmaf(f2, r2.x, fmaf(f1, r1.x, f0 * r0.x)));
    o.y = fmaf(f3, r3.y, fmaf(f2, r2.y, fmaf(f1, r1.y, f0 * r0.y)));
    o.z = fmaf(f3, r3.z, fmaf(f2, r2.z, fmaf(f1, r1.z, f0 * r0.z)));
    o.w = fmaf(f3, r3.w, fmaf(f2, r2.w, fmaf(f1, r1.w, f0 * r0.w)));

    ((float4*)(pacc + ((size_t)b * P_CHUNKS + p) * DIM))[t] = o;
    if (t == 0) {
        pm[b * P_CHUNKS + p] = M;
        pl[b * P_CHUNKS + p] =
            fmaf(f3, slw[3], fmaf(f2, slw[2], fmaf(f1, slw[1], f0 * slw[0])));
    }
}

// ---------------------------------------------------------------------------
// Combine 32 chunk-partials for batch b; write s_tilde into cat[:, :1024]
// and copy h into cat[:, 1024:]. Grid (32 batches x 4 d-quarters), 256 thr.
// ---------------------------------------------------------------------------
__global__ __launch_bounds__(256) void combine(
    const float* __restrict__ pacc, const float* __restrict__ pm,
    const float* __restrict__ pl, const float* __restrict__ h,
    float* __restrict__ cat)
{
    const int b = blockIdx.x;
    const int q = blockIdx.y;
    const int t = threadIdx.x;

    __shared__ float fsc[P_CHUNKS];
    __shared__ float Linv;

    if (t < 32) {
        const float mv = pm[b * P_CHUNKS + t];
        const float lv = pl[b * P_CHUNKS + t];
        float mx = mv;
#pragma unroll
        for (int off = 16; off > 0; off >>= 1)
            mx = fmaxf(mx, __shfl_xor(mx, off, 64));   // stays within lanes 0-31
        const float f = __expf(mv - mx);
        fsc[t] = f;
        float L = lv * f;
#pragma unroll
        for (int off = 16; off > 0; off >>= 1) L += __shfl_xor(L, off, 64);
        if (t == 0) Linv = 1.0f / L;
    }
    __syncthreads();

    const int d = q * 256 + t;
    const float* pb = pacc + (size_t)b * P_CHUNKS * DIM + d;
    float s0 = 0.f, s1 = 0.f, s2 = 0.f, s3 = 0.f;
#pragma unroll
    for (int pp = 0; pp < P_CHUNKS; pp += 4) {
        s0 = fmaf(fsc[pp + 0], pb[(size_t)(pp + 0) * DIM], s0);
        s1 = fmaf(fsc[pp + 1], pb[(size_t)(pp + 1) * DIM], s1);
        s2 = fmaf(fsc[pp + 2], pb[(size_t)(pp + 2) * DIM], s2);
        s3 = fmaf(fsc[pp + 3], pb[(size_t)(pp + 3) * DIM], s3);
    }
    const float sum = (s0 + s1) + (s2 + s3);

    cat[(size_t)b * (2 * DIM) + d]       = sum * Linv;
    cat[(size_t)b * (2 * DIM) + DIM + d] = h[(size_t)b * DIM + d];
}

// ---------------------------------------------------------------------------
extern "C" void kernel_launch(void* const* d_in, const int* in_sizes, int n_in,
                              void* d_out, int out_size, void* d_ws, size_t ws_size,
                              hipStream_t stream)
{
    const float* input = (const float*)d_in[0];  // [S, B, D]
    const float* h     = (const float*)d_in[1];  // [B, D]
    const float* Wi    = (const float*)d_in[2];  // [D, D]
    const float* Wo    = (const float*)d_in[3];  // [D, 2D]
    float* out = (float*)d_out;                  // [B, D]

    // Workspace carve (floats): semi | pacc | pm | pl | cat  (~4.4 MiB)
    float* ws   = (float*)d_ws;
    float* semi = ws;                                       // 32*1024
    float* pacc = semi + 32 * 1024;                         // 32*32*1024
    float* pm   = pacc + (size_t)32 * P_CHUNKS * 1024;      // 32*32
    float* pl   = pm + 32 * P_CHUNKS;                       // 32*32
    float* cat  = pl + 32 * P_CHUNKS;                       // 32*2048

    // 1) semi = h @ Wi.T   (K=1024, Dout=1024)
    hipLaunchKernelGGL(gemm_skinny, dim3(256), dim3(256), 0, stream,
                       h, Wi, semi, 1024, 1024, 0);
    // 2) fused logits + online softmax + weighted-sum partials (reads input once)
    hipLaunchKernelGGL(attn_partial, dim3(P_CHUNKS, BATCH), dim3(256), 0, stream,
                       input, semi, pacc, pm, pl);
    // 3) combine partials -> cat = [s_tilde, h]
    hipLaunchKernelGGL(combine, dim3(BATCH, 4), dim3(256), 0, stream,
                       pacc, pm, pl, h, cat);
    // 4) out = tanh(cat @ Wo.T)   (K=2048, Dout=1024)
    hipLaunchKernelGGL(gemm_skinny, dim3(256), dim3(256), 0, stream,
                       cat, Wo, out, 2048, 1024, 1);
}